// Round 1
// baseline (570.957 us; speedup 1.0000x reference)
//
#include <hip/hip_runtime.h>
#include <hip/hip_bf16.h>
#include <stdint.h>

#define H 512
#define SEQ 2048
#define BATCH 64
#define BH (BATCH * H)

typedef float f32x4 __attribute__((ext_vector_type(4)));
typedef short bf16x8 __attribute__((ext_vector_type(8)));

__device__ __forceinline__ unsigned short f2bf(float f) {
    // RTNE f32 -> bf16 (inputs finite; no NaN handling needed)
    unsigned int u = __float_as_uint(f);
    u += 0x7fff + ((u >> 16) & 1);
    return (unsigned short)(u >> 16);
}

// ---------- prep: W_t[n][k] = bf16(W[k][n])  and  WR = mean_sent_batch @ W_h ----------
__global__ __launch_bounds__(256) void prep_kernel(const float* __restrict__ W,
                                                   const float* __restrict__ mean_sb,
                                                   const float* __restrict__ W_h,
                                                   unsigned short* __restrict__ W_t,
                                                   float* __restrict__ WR) {
    int bid = blockIdx.x;
    int tid = threadIdx.x;
    if (bid < 1024) {
        int idx = bid * 256 + tid;   // 262144 elements
        int k = idx >> 9;
        int n = idx & 511;
        W_t[n * H + k] = f2bf(W[k * H + n]);   // coalesced read, scattered write (L2 absorbs, 1MB)
    } else {
        int b = bid - 1024;          // 64 blocks
        float a0 = 0.f, a1 = 0.f;
        for (int k = 0; k < H; ++k) {
            float m = mean_sb[b * H + k];      // wave-uniform -> scalar load
            a0 += m * W_h[k * H + tid];
            a1 += m * W_h[k * H + tid + 256];
        }
        WR[b * H + tid] = a0;
        WR[b * H + tid + 256] = a1;
    }
}

// ---------- scores[b][s] = ctx . tanh( (mask*sent)[s,b,:] @ W + WR[b,:] ) ----------
// Block: 64 s-rows of one batch b. 4 waves split N (128 cols each); each wave does all 64 rows.
__global__ __launch_bounds__(256) void scores_kernel(const float* __restrict__ sent,
                                                     const float* __restrict__ mask,
                                                     const unsigned short* __restrict__ W_t,
                                                     const float* __restrict__ WR,
                                                     const float* __restrict__ ctx,
                                                     float* __restrict__ scores) {
    __shared__ uint4 A_lds[64 * 64];   // 64 rows x 64 chunks(8 bf16) = 64 KiB, XOR-swizzled
    const int b = blockIdx.y;
    const int s0 = blockIdx.x * 64;
    const int tid = threadIdx.x;
    const int wave = tid >> 6;
    const int lane = tid & 63;
    const int lg = lane >> 4;    // 4-lane-group id (k sub-chunk)
    const int ln = lane & 15;    // row-within-subtile / col id

    // ---- stage A: 64 rows x 512 k, f32 -> bf16, chunk-swizzled (c ^= row&7) ----
    #pragma unroll 4
    for (int pass = 0; pass < 16; ++pass) {
        int row = pass * 4 + wave;     // one row per wave per pass
        int c = lane;                  // 64 chunks of 8 floats
        const float* src = sent + (size_t)(s0 + row) * BH + b * H + c * 8;
        float4 f0 = *(const float4*)src;
        float4 f1 = *(const float4*)(src + 4);
        float m = mask[(s0 + row) * BATCH + b];   // wave-uniform
        union { unsigned short h[8]; uint4 v; } u;
        u.h[0] = f2bf(f0.x * m); u.h[1] = f2bf(f0.y * m);
        u.h[2] = f2bf(f0.z * m); u.h[3] = f2bf(f0.w * m);
        u.h[4] = f2bf(f1.x * m); u.h[5] = f2bf(f1.y * m);
        u.h[6] = f2bf(f1.z * m); u.h[7] = f2bf(f1.w * m);
        A_lds[row * 64 + (c ^ (row & 7))] = u.v;
    }
    __syncthreads();

    float p[4][4];   // per-lane partial scores: [m-subtile][reg] ; row = m*16 + lg*4 + r
    #pragma unroll
    for (int m = 0; m < 4; ++m)
        #pragma unroll
        for (int r = 0; r < 4; ++r) p[m][r] = 0.f;

    const int n_wave = wave * 128;

    #pragma unroll 1
    for (int half = 0; half < 2; ++half) {
        const int n0 = n_wave + half * 64;
        f32x4 acc[4][4];   // [m-subtile][n-chunk q]
        #pragma unroll
        for (int m = 0; m < 4; ++m)
            #pragma unroll
            for (int q = 0; q < 4; ++q) acc[m][q] = (f32x4){0.f, 0.f, 0.f, 0.f};

        // precompute bases (static-indexed arrays, fully unrolled consumers)
        int arow[4], arowx[4];
        const unsigned short* wbase[4];
        #pragma unroll
        for (int m = 0; m < 4; ++m) {
            int row = m * 16 + ln;
            arow[m] = row * 64;
            arowx[m] = row & 7;
        }
        #pragma unroll
        for (int q = 0; q < 4; ++q)
            wbase[q] = W_t + (size_t)(n0 + q * 16 + ln) * H + lg * 8;

        #pragma unroll 2
        for (int ks = 0; ks < 16; ++ks) {
            bf16x8 a[4], bq[4];
            #pragma unroll
            for (int m = 0; m < 4; ++m) {
                uint4 raw = A_lds[arow[m] + ((4 * ks + lg) ^ arowx[m])];
                union { uint4 v; bf16x8 f; } uu; uu.v = raw;
                a[m] = uu.f;
            }
            #pragma unroll
            for (int q = 0; q < 4; ++q)
                bq[q] = *(const bf16x8*)(wbase[q] + ks * 32);
            #pragma unroll
            for (int m = 0; m < 4; ++m)
                #pragma unroll
                for (int q = 0; q < 4; ++q)
                    acc[m][q] = __builtin_amdgcn_mfma_f32_16x16x32_bf16(a[m], bq[q], acc[m][q], 0, 0, 0);
        }

        // epilogue: tanh(WY + WR) * ctx, accumulate per-row partials
        #pragma unroll
        for (int q = 0; q < 4; ++q) {
            int n = n0 + q * 16 + ln;
            float wr = WR[b * H + n];
            float cx = ctx[n];
            #pragma unroll
            for (int m = 0; m < 4; ++m)
                #pragma unroll
                for (int r = 0; r < 4; ++r) {
                    float x = acc[m][q][r] + wr;
                    float e = __expf(2.0f * x);                       // tanh = 1 - 2/(e^2x+1); safe at +-inf
                    p[m][r] += cx * (1.0f - 2.0f * __builtin_amdgcn_rcpf(e + 1.0f));
                }
        }
    }

    // reduce over the 16 n-columns held by lanes sharing lg
    #pragma unroll
    for (int m = 0; m < 4; ++m)
        #pragma unroll
        for (int r = 0; r < 4; ++r) {
            float v = p[m][r];
            v += __shfl_xor(v, 1, 16);
            v += __shfl_xor(v, 2, 16);
            v += __shfl_xor(v, 4, 16);
            v += __shfl_xor(v, 8, 16);
            p[m][r] = v;
        }

    // cross-wave combine (waves hold disjoint n-ranges of the SAME rows)
    __syncthreads();                     // done reading A_lds
    float* sp = (float*)A_lds;           // reuse LDS
    if (ln == 0) {
        #pragma unroll
        for (int m = 0; m < 4; ++m)
            #pragma unroll
            for (int r = 0; r < 4; ++r)
                sp[wave * 64 + m * 16 + lg * 4 + r] = p[m][r];
    }
    __syncthreads();
    if (tid < 64) {
        float v = sp[tid] + sp[64 + tid] + sp[128 + tid] + sp[192 + tid];
        scores[b * SEQ + s0 + tid] = v;
    }
}

// ---------- softmax over S per batch ----------
__global__ __launch_bounds__(256) void softmax_kernel(const float* __restrict__ scores,
                                                      float* __restrict__ alpha) {
    __shared__ float red[8];
    int b = blockIdx.x, tid = threadIdx.x;
    const float* srow = scores + b * SEQ;
    float4 v0 = *(const float4*)(srow + tid * 8);
    float4 v1 = *(const float4*)(srow + tid * 8 + 4);
    float mx = fmaxf(fmaxf(fmaxf(v0.x, v0.y), fmaxf(v0.z, v0.w)),
                     fmaxf(fmaxf(v1.x, v1.y), fmaxf(v1.z, v1.w)));
    #pragma unroll
    for (int m = 1; m <= 32; m <<= 1) mx = fmaxf(mx, __shfl_xor(mx, m, 64));
    int wave = tid >> 6, lane = tid & 63;
    if (lane == 0) red[wave] = mx;
    __syncthreads();
    mx = fmaxf(fmaxf(red[0], red[1]), fmaxf(red[2], red[3]));
    float e[8];
    e[0] = __expf(v0.x - mx); e[1] = __expf(v0.y - mx);
    e[2] = __expf(v0.z - mx); e[3] = __expf(v0.w - mx);
    e[4] = __expf(v1.x - mx); e[5] = __expf(v1.y - mx);
    e[6] = __expf(v1.z - mx); e[7] = __expf(v1.w - mx);
    float sum = ((e[0] + e[1]) + (e[2] + e[3])) + ((e[4] + e[5]) + (e[6] + e[7]));
    #pragma unroll
    for (int m = 1; m <= 32; m <<= 1) sum += __shfl_xor(sum, m, 64);
    if (lane == 0) red[4 + wave] = sum;
    __syncthreads();
    float inv = 1.0f / (((red[4] + red[5]) + (red[6] + red[7])));
    float4 o0 = {e[0] * inv, e[1] * inv, e[2] * inv, e[3] * inv};
    float4 o1 = {e[4] * inv, e[5] * inv, e[6] * inv, e[7] * inv};
    *(float4*)(alpha + b * SEQ + tid * 8) = o0;
    *(float4*)(alpha + b * SEQ + tid * 8 + 4) = o1;
}

// ---------- out[b][h] = sum_s alpha[b][s] * mask[s][b] * sent[s][b][h] ----------
__global__ __launch_bounds__(256) void wsum_kernel(const float* __restrict__ sent,
                                                   const float* __restrict__ mask,
                                                   const float* __restrict__ alpha,
                                                   float* __restrict__ out) {
    int b = blockIdx.y;
    int chunk = blockIdx.x;        // 16 chunks of 128 s
    int tid = threadIdx.x;         // 256 threads, 2 h each
    int h = tid * 2;
    float a0 = 0.f, a1 = 0.f;
    int s_base = chunk * 128;
    #pragma unroll 4
    for (int i = 0; i < 128; ++i) {
        int s = s_base + i;
        float am = alpha[b * SEQ + s] * mask[s * BATCH + b];   // block-uniform -> scalar
        const float* sp = sent + (size_t)s * BH + b * H + h;
        float2 v = *(const float2*)sp;
        a0 += am * v.x;
        a1 += am * v.y;
    }
    atomicAdd(&out[b * H + h], a0);
    atomicAdd(&out[b * H + h + 1], a1);
}

extern "C" void kernel_launch(void* const* d_in, const int* in_sizes, int n_in,
                              void* d_out, int out_size, void* d_ws, size_t ws_size,
                              hipStream_t stream) {
    const float* sent    = (const float*)d_in[0];   // (S,B,H)
    const float* mean_sb = (const float*)d_in[1];   // (B,H)
    const float* mask    = (const float*)d_in[2];   // (S,B)
    const float* W       = (const float*)d_in[3];   // (H,H)
    const float* W_h     = (const float*)d_in[4];   // (H,H)
    const float* ctx     = (const float*)d_in[5];   // (H)
    float* out = (float*)d_out;                     // (B,H) f32

    char* ws = (char*)d_ws;
    unsigned short* W_t = (unsigned short*)(ws);          // 512 KiB bf16 W^T
    float* WR           = (float*)(ws + 524288);          // 128 KiB
    float* scores       = (float*)(ws + 655360);          // 512 KiB
    float* alpha        = (float*)(ws + 1179648);         // 512 KiB

    hipMemsetAsync(d_out, 0, (size_t)out_size * sizeof(float), stream);
    prep_kernel<<<1088, 256, 0, stream>>>(W, mean_sb, W_h, W_t, WR);
    scores_kernel<<<dim3(32, 64), 256, 0, stream>>>(sent, mask, W_t, WR, ctx, scores);
    softmax_kernel<<<64, 256, 0, stream>>>(scores, alpha);
    wsum_kernel<<<dim3(16, 64), 256, 0, stream>>>(sent, mask, alpha, out);
}

// Round 5
// 543.257 us; speedup vs baseline: 1.0510x; 1.0510x over previous
//
#include <hip/hip_runtime.h>
#include <hip/hip_bf16.h>
#include <stdint.h>

#define H 512
#define SEQ 2048
#define BATCH 64
#define BH (BATCH * H)

typedef float f32x4 __attribute__((ext_vector_type(4)));
typedef short bf16x8 __attribute__((ext_vector_type(8)));

__device__ __forceinline__ unsigned short f2bf(float f) {
    // RTNE f32 -> bf16 (inputs finite; no NaN handling needed)
    unsigned int u = __float_as_uint(f);
    u += 0x7fff + ((u >> 16) & 1);
    return (unsigned short)(u >> 16);
}

// ---------- prep ----------
// Wf fragment-major: for n-subtile t(0..31), k-step ks(0..15), lane(0..63):
//   Wf[(t*16+ks)*64 + lane] = bf16x8 of W[k = ks*32 + (lane>>4)*8 + j][n = t*16 + (lane&15)]
// -> inner-loop B-frag load is ONE contiguous 1KB wave read (vs 16 scattered lines before).
// Also WR = mean_sent_batch @ W_h.
__global__ __launch_bounds__(256) void prep_kernel(const float* __restrict__ W,
                                                   const float* __restrict__ mean_sb,
                                                   const float* __restrict__ W_h,
                                                   uint4* __restrict__ Wf,
                                                   float* __restrict__ WR) {
    int bid = blockIdx.x;
    int tid = threadIdx.x;
    if (bid < 128) {
        int c = bid * 256 + tid;        // 32768 bf16x8 chunks
        int lane = c & 63;
        int ks = (c >> 6) & 15;
        int t = c >> 10;
        int lg = lane >> 4, ln = lane & 15;
        int n = t * 16 + ln;
        int k0 = ks * 32 + lg * 8;
        union { unsigned short h[8]; uint4 v; } u;
        #pragma unroll
        for (int j = 0; j < 8; ++j)
            u.h[j] = f2bf(W[(size_t)(k0 + j) * H + n]);   // 16-lane groups hit same 64B line
        Wf[c] = u.v;
    } else {
        int b = bid - 128;              // 64 blocks
        float a0 = 0.f, a1 = 0.f;
        #pragma unroll 4
        for (int k = 0; k < H; ++k) {
            float m = mean_sb[b * H + k];      // wave-uniform
            a0 += m * W_h[k * H + tid];
            a1 += m * W_h[k * H + tid + 256];
        }
        WR[b * H + tid] = a0;
        WR[b * H + tid + 256] = a1;
    }
}

// ---------- scores[b][s] = ctx . tanh( (mask*sent)[s,b,:] @ W + WR[b,:] ) ----------
// Block: 512 threads = 8 waves, 64 s-rows of one b. Wave w owns n in [w*64, w*64+64).
// LDS 64KB A-tile (bf16, XOR-swizzled) -> 2 blocks/CU, 16 waves/CU.
__global__ __launch_bounds__(512, 4) void scores_kernel(const float* __restrict__ sent,
                                                        const float* __restrict__ mask,
                                                        const uint4* __restrict__ Wf,
                                                        const float* __restrict__ WR,
                                                        const float* __restrict__ ctx,
                                                        float* __restrict__ scores) {
    __shared__ uint4 A_lds[64 * 64];   // 64 rows x 64 chunks(8 bf16) = 64 KiB
    const int b = blockIdx.y;
    const int s0 = blockIdx.x * 64;
    const int tid = threadIdx.x;
    const int wave = tid >> 6;
    const int lane = tid & 63;
    const int lg = lane >> 4;    // k sub-chunk within k-step
    const int ln = lane & 15;    // row / col id within 16-subtile

    // ---- stage A: 64 rows x 512 k, f32 -> bf16(mask applied), chunk-swizzled ----
    #pragma unroll
    for (int pass = 0; pass < 8; ++pass) {
        int row = pass * 8 + wave;
        const float* src = sent + (size_t)(s0 + row) * BH + b * H + lane * 8;
        float4 f0 = *(const float4*)src;
        float4 f1 = *(const float4*)(src + 4);
        float m = mask[(s0 + row) * BATCH + b];   // wave-uniform
        union { unsigned short h[8]; uint4 v; } u;
        u.h[0] = f2bf(f0.x * m); u.h[1] = f2bf(f0.y * m);
        u.h[2] = f2bf(f0.z * m); u.h[3] = f2bf(f0.w * m);
        u.h[4] = f2bf(f1.x * m); u.h[5] = f2bf(f1.y * m);
        u.h[6] = f2bf(f1.z * m); u.h[7] = f2bf(f1.w * m);
        A_lds[row * 64 + (lane ^ (row & 7))] = u.v;
    }
    __syncthreads();

    f32x4 acc[4][4];   // [m-subtile][q(n-subtile within wave)]
    #pragma unroll
    for (int m = 0; m < 4; ++m)
        #pragma unroll
        for (int q = 0; q < 4; ++q) acc[m][q] = (f32x4){0.f, 0.f, 0.f, 0.f};

    int arow[4], arx[4];
    #pragma unroll
    for (int m = 0; m < 4; ++m) {
        int row = m * 16 + ln;
        arow[m] = row * 64;
        arx[m] = row & 7;
    }
    // B base: chunk index (t*16+ks)*64+lane with t = wave*4+q
    const uint4* Bp = Wf + (size_t)wave * 4096 + lane;

    #pragma unroll 2
    for (int ks = 0; ks < 16; ++ks) {
        bf16x8 a[4], bq[4];
        #pragma unroll
        for (int m = 0; m < 4; ++m) {
            uint4 raw = A_lds[arow[m] + ((4 * ks + lg) ^ arx[m])];
            union { uint4 v; bf16x8 f; } uu; uu.v = raw;
            a[m] = uu.f;
        }
        #pragma unroll
        for (int q = 0; q < 4; ++q) {
            uint4 raw = Bp[q * 1024 + ks * 64];   // 1KB contiguous per wave
            union { uint4 v; bf16x8 f; } uu; uu.v = raw;
            bq[q] = uu.f;
        }
        #pragma unroll
        for (int m = 0; m < 4; ++m)
            #pragma unroll
            for (int q = 0; q < 4; ++q)
                acc[m][q] = __builtin_amdgcn_mfma_f32_16x16x32_bf16(a[m], bq[q], acc[m][q], 0, 0, 0);
    }

    // epilogue: tanh(WY + WR) * ctx -> per-row partials
    float p[4][4];
    #pragma unroll
    for (int m = 0; m < 4; ++m)
        #pragma unroll
        for (int r = 0; r < 4; ++r) p[m][r] = 0.f;

    #pragma unroll
    for (int q = 0; q < 4; ++q) {
        int n = wave * 64 + q * 16 + ln;
        float wr = WR[b * H + n];
        float cx = ctx[n];
        #pragma unroll
        for (int m = 0; m < 4; ++m)
            #pragma unroll
            for (int r = 0; r < 4; ++r) {
                float x = acc[m][q][r] + wr;
                float e = __expf(2.0f * x);                 // tanh = 1 - 2/(e^2x+1)
                p[m][r] += cx * (1.0f - 2.0f * __builtin_amdgcn_rcpf(e + 1.0f));
            }
    }

    // reduce over the 16 n-columns (lanes sharing lg)
    #pragma unroll
    for (int m = 0; m < 4; ++m)
        #pragma unroll
        for (int r = 0; r < 4; ++r) {
            float v = p[m][r];
            v += __shfl_xor(v, 1, 16);
            v += __shfl_xor(v, 2, 16);
            v += __shfl_xor(v, 4, 16);
            v += __shfl_xor(v, 8, 16);
            p[m][r] = v;
        }

    // cross-wave combine (8 waves hold disjoint n-ranges of the SAME 64 rows)
    __syncthreads();                     // done reading A_lds
    float* sp = (float*)A_lds;
    if (ln == 0) {
        #pragma unroll
        for (int m = 0; m < 4; ++m)
            #pragma unroll
            for (int r = 0; r < 4; ++r)
                sp[wave * 64 + m * 16 + lg * 4 + r] = p[m][r];
    }
    __syncthreads();
    if (tid < 64) {
        float v = 0.f;
        #pragma unroll
        for (int w = 0; w < 8; ++w) v += sp[w * 64 + tid];
        scores[b * SEQ + s0 + tid] = v;
    }
}

// ---------- softmax over S per batch; folds mask into alpha' = alpha * mask ----------
__global__ __launch_bounds__(256) void softmax_kernel(const float* __restrict__ scores,
                                                      const float* __restrict__ mask,
                                                      float* __restrict__ alphap) {
    __shared__ float red[8];
    int b = blockIdx.x, tid = threadIdx.x;
    const float* srow = scores + b * SEQ;
    float4 v0 = *(const float4*)(srow + tid * 8);
    float4 v1 = *(const float4*)(srow + tid * 8 + 4);
    float mx = fmaxf(fmaxf(fmaxf(v0.x, v0.y), fmaxf(v0.z, v0.w)),
                     fmaxf(fmaxf(v1.x, v1.y), fmaxf(v1.z, v1.w)));
    #pragma unroll
    for (int m = 1; m <= 32; m <<= 1) mx = fmaxf(mx, __shfl_xor(mx, m, 64));
    int wave = tid >> 6, lane = tid & 63;
    if (lane == 0) red[wave] = mx;
    __syncthreads();
    mx = fmaxf(fmaxf(red[0], red[1]), fmaxf(red[2], red[3]));
    float e[8];
    e[0] = __expf(v0.x - mx); e[1] = __expf(v0.y - mx);
    e[2] = __expf(v0.z - mx); e[3] = __expf(v0.w - mx);
    e[4] = __expf(v1.x - mx); e[5] = __expf(v1.y - mx);
    e[6] = __expf(v1.z - mx); e[7] = __expf(v1.w - mx);
    float sum = ((e[0] + e[1]) + (e[2] + e[3])) + ((e[4] + e[5]) + (e[6] + e[7]));
    #pragma unroll
    for (int m = 1; m <= 32; m <<= 1) sum += __shfl_xor(sum, m, 64);
    if (lane == 0) red[4 + wave] = sum;
    __syncthreads();
    float inv = 1.0f / (((red[4] + red[5]) + (red[6] + red[7])));
    int s8 = tid * 8;
    float4 o0, o1;
    o0.x = e[0] * inv * mask[(s8 + 0) * BATCH + b];
    o0.y = e[1] * inv * mask[(s8 + 1) * BATCH + b];
    o0.z = e[2] * inv * mask[(s8 + 2) * BATCH + b];
    o0.w = e[3] * inv * mask[(s8 + 3) * BATCH + b];
    o1.x = e[4] * inv * mask[(s8 + 4) * BATCH + b];
    o1.y = e[5] * inv * mask[(s8 + 5) * BATCH + b];
    o1.z = e[6] * inv * mask[(s8 + 6) * BATCH + b];
    o1.w = e[7] * inv * mask[(s8 + 7) * BATCH + b];
    *(float4*)(alphap + b * SEQ + s8) = o0;
    *(float4*)(alphap + b * SEQ + s8 + 4) = o1;
}

// ---------- out[b][h] = sum_s alpha'[b][s] * sent[s][b][h] ----------
__global__ __launch_bounds__(256) void wsum_kernel(const float* __restrict__ sent,
                                                   const float* __restrict__ alphap,
                                                   float* __restrict__ out) {
    int b = blockIdx.y;
    int chunk = blockIdx.x;            // 32 chunks of 64 s
    int tid = threadIdx.x;
    int sub = tid >> 7;                // 2 s-rows in flight
    int hq = (tid & 127) * 4;
    int sbase = chunk * 64 + sub;
    f32x4 acc = {0.f, 0.f, 0.f, 0.f};
    #pragma unroll 4
    for (int i = 0; i < 32; ++i) {
        int s = sbase + i * 2;
        float am = alphap[b * SEQ + s];
        float4 v = *(const float4*)(sent + (size_t)s * BH + b * H + hq);
        acc.x += am * v.x; acc.y += am * v.y;
        acc.z += am * v.z; acc.w += am * v.w;
    }
    atomicAdd(&out[b * H + hq + 0], acc.x);
    atomicAdd(&out[b * H + hq + 1], acc.y);
    atomicAdd(&out[b * H + hq + 2], acc.z);
    atomicAdd(&out[b * H + hq + 3], acc.w);
}

extern "C" void kernel_launch(void* const* d_in, const int* in_sizes, int n_in,
                              void* d_out, int out_size, void* d_ws, size_t ws_size,
                              hipStream_t stream) {
    const float* sent    = (const float*)d_in[0];   // (S,B,H)
    const float* mean_sb = (const float*)d_in[1];   // (B,H)
    const float* mask    = (const float*)d_in[2];   // (S,B)
    const float* W       = (const float*)d_in[3];   // (H,H)
    const float* W_h     = (const float*)d_in[4];   // (H,H)
    const float* ctx     = (const float*)d_in[5];   // (H)
    float* out = (float*)d_out;                     // (B,H) f32

    char* ws = (char*)d_ws;
    uint4* Wf    = (uint4*)(ws);                    // 512 KiB fragment-major bf16 W
    float* WR    = (float*)(ws + 524288);           // 128 KiB
    float* scores = (float*)(ws + 655360);          // 512 KiB
    float* alphap = (float*)(ws + 1179648);         // 512 KiB

    hipMemsetAsync(d_out, 0, (size_t)out_size * sizeof(float), stream);
    prep_kernel<<<192, 256, 0, stream>>>(W, mean_sb, W_h, Wf, WR);
    scores_kernel<<<dim3(32, 64), 512, 0, stream>>>(sent, mask, Wf, WR, ctx, scores);
    softmax_kernel<<<64, 256, 0, stream>>>(scores, mask, alphap);
    wsum_kernel<<<dim3(32, 64), 256, 0, stream>>>(sent, alphap, out);
}